// Round 8
// baseline (58.804 us; speedup 1.0000x reference)
//
#include <hip/hip_runtime.h>

// YOLOv1 loss, MI355X. input/target (4096,14,14,30) f32 -> scalar f32 (loss/4096).
// Round 8: depth experiment. R3 topology (independent 1-wave streams, width-16
// global_load_lds, counted vmcnt, no inter-wave deps) but 2 waves/block with
// PRIVATE double-buffers -> 122,880 B LDS/block -> 1 block/CU -> 120 KB
// outstanding per CU (2x R3/R6's 60 KB, which both hit the same 4.5 TB/s).
// Compute: R6-validated conflict-free 2-lanes-per-cell stride-15 mapping.

#define COORD 5.0f
#define NOOBJ 0.5f

#define NCELLS   (4096 * 14 * 14)   // 802816
#define CPC      128                // cells per chunk (per wave)
#define CHB      (CPC * 120)        // 15360 B per tensor per chunk
#define NCHUNKS  (NCELLS / CPC)     // 6272
#define NSTREAM  512                // independent wave streams (256 blocks x 2)

__device__ __forceinline__ float d2f(float a, float b) { float d = a - b; return d * d; }
__device__ __forceinline__ float sqd(float a, float b) {
    // (sqrt(a)-sqrt(b))^2 = a + b - 2*sqrt(a*b);  a,b >= 0
    return a + b - 2.0f * sqrtf(a * b);
}

__global__ __launch_bounds__(128) void yolo_loss_kernel(
    const float* __restrict__ inp,
    const float* __restrict__ tgt,
    float* __restrict__ out,
    float inv_n)
{
    // [wave][dbuf][tensor][bytes] : private per-wave pipelines, 122880 B total
    __shared__ __align__(16) char smem[2][2][2][CHB];
    __shared__ float wsum[2];

    const int tid  = threadIdx.x;
    const int lane = tid & 63;
    const int wid  = tid >> 6;
    const int wv   = blockIdx.x * 2 + wid;          // stream id 0..511

    const char* gi0 = (const char*)inp + (size_t)lane * 16;
    const char* gt0 = (const char*)tgt + (size_t)lane * 16;

    // stage chunk c (both tensors, 30 width-16 instructions) into buffer b
    auto stage = [&](int b, int c) {
        const char* gi = gi0 + (size_t)c * CHB;
        const char* gt = gt0 + (size_t)c * CHB;
        char* li = &smem[wid][b][0][0];
        char* lt = &smem[wid][b][1][0];
#pragma unroll
        for (int k = 0; k < 15; ++k) {
            __builtin_amdgcn_global_load_lds(
                (const __attribute__((address_space(1))) void*)(gi + k * 1024),
                (__attribute__((address_space(3))) void*)(li + k * 1024), 16, 0, 0);
            __builtin_amdgcn_global_load_lds(
                (const __attribute__((address_space(1))) void*)(gt + k * 1024),
                (__attribute__((address_space(3))) void*)(lt + k * 1024), 16, 0, 0);
        }
    };

    float acc = 0.0f;
    int c = wv;
    stage(0, c);                     // 30 outstanding
    stage(1, c + NSTREAM);           // 60 outstanding (wv+512 <= 1023 < 6272 always)
    int cur = 0;

    const int half = lane & 1;

    for (; c < NCHUNKS; c += NSTREAM) {
        const int cpre = c + 2 * NSTREAM;
        if (cpre < NCHUNKS) {
            asm volatile("s_waitcnt vmcnt(30)" ::: "memory");   // chunk c's 30 landed
        } else {
            asm volatile("s_waitcnt vmcnt(0)" ::: "memory");    // tail drain
        }

        const float* li = (const float*)&smem[wid][cur][0][0];
        const float* lt = (const float*)&smem[wid][cur][1][0];

#pragma unroll
        for (int pass = 0; pass < 4; ++pass) {
            const int p    = (lane >> 1) + 32 * pass;     // cell 0..127
            const int base = 15 * lane + 960 * pass;      // = 30p + 15*half
            const float* ip = li + base;
            const float* tp = lt + base;

            // masks from target conf (pair-broadcast reads, conflict-free)
            float t0 = lt[p * 30];
            float t1 = lt[p * 30 + 1];
            bool o0 = (t0 == 1.0f), o1 = (t1 == 1.0f);
            float f0 = o0 ? 1.0f : 0.0f;
            float f1 = (o1 && !o0) ? 1.0f : 0.0f;
            float h  = (o0 || o1) ? 1.0f : 0.0f;
            float nf = 1.0f - h;

            if (half == 0) {
                // channels 0..14: conf0 conf1 | x0 y0 w0 h0 | x1 y1 w1 h1 | cls0..4
                float s0  = d2f(ip[0], tp[0]);
                float s1  = d2f(ip[1], tp[1]);
                float xy0 = d2f(ip[2], tp[2]) + d2f(ip[3], tp[3]);
                float wh0 = sqd(ip[4], tp[4]) + sqd(ip[5], tp[5]);
                float xy1 = d2f(ip[6], tp[6]) + d2f(ip[7], tp[7]);
                float wh1 = sqd(ip[8], tp[8]) + sqd(ip[9], tp[9]);
                float cls = d2f(ip[10], tp[10]) + d2f(ip[11], tp[11]) + d2f(ip[12], tp[12])
                          + d2f(ip[13], tp[13]) + d2f(ip[14], tp[14]);
                acc += COORD * (f0 * (xy0 + wh0) + f1 * (xy1 + wh1))
                     + f0 * s0 + f1 * s1
                     + NOOBJ * nf * (s0 + s1)
                     + h * cls;
            } else {
                // channels 15..29: cls5..cls19
                float cls = 0.0f;
#pragma unroll
                for (int j = 0; j < 15; ++j)
                    cls += d2f(ip[j], tp[j]);
                acc += h * cls;
            }
        }

        // all ds_reads of buf `cur` retired before its glds overwrite can land
        asm volatile("s_waitcnt lgkmcnt(0)" ::: "memory");
        if (cpre < NCHUNKS) stage(cur, cpre);
        cur ^= 1;
    }

    // ---- reduction: wave shfl -> LDS -> one atomic per block ----
#pragma unroll
    for (int off = 32; off > 0; off >>= 1)
        acc += __shfl_down(acc, off, 64);
    if (lane == 0) wsum[wid] = acc;
    __syncthreads();
    if (tid == 0) atomicAdd(out, (wsum[0] + wsum[1]) * inv_n);
}

extern "C" void kernel_launch(void* const* d_in, const int* in_sizes, int n_in,
                              void* d_out, int out_size, void* d_ws, size_t ws_size,
                              hipStream_t stream) {
    const float* inp = (const float*)d_in[0];
    const float* tgt = (const float*)d_in[1];
    float* out = (float*)d_out;

    hipMemsetAsync(out, 0, sizeof(float), stream);
    yolo_loss_kernel<<<256, 128, 0, stream>>>(inp, tgt, out, 1.0f / 4096.0f);
}